// Round 11
// baseline (1829.674 us; speedup 1.0000x reference)
//
#include <hip/hip_runtime.h>

typedef _Float16 half_t;
typedef __attribute__((ext_vector_type(8))) _Float16 half8;
typedef __attribute__((ext_vector_type(4))) float f32x4;

#define BB 64
#define II 512
#define DD 128
#define NN 32
#define OO 64

// DIAGNOSTIC ROUND: reps-loops make each kernel's dispatch long enough to
// displace the harness poison-fills (~330us) from rocprof's top-5 so we
// finally see per-kernel counters. Math identical & idempotent per rep.
#define REPS_K1 4
#define REPS_R0 24
#define REPS_RR 24

// load 8 contiguous u-elements (fp16) as fp32
__device__ inline void load8u(const half_t* p, float* a) {
  half8 v = *(const half8*)p;
  #pragma unroll
  for (int e = 0; e < 8; ++e) a[e] = (float)v[e];
}

// ---------------------------------------------------------------------------
// K1: u[b,n,i,o] = sum_d x[b,i,d] * W[n,i,o,d] via fp16 MFMA (round-10 body,
// validated) wrapped in a reps loop.
// ---------------------------------------------------------------------------
__global__ __launch_bounds__(256) void k_compute_u(
    const float* __restrict__ x, const float* __restrict__ W,
    half_t* __restrict__ u, int reps)
{
  __shared__ unsigned char AsCs[16384] __attribute__((aligned(16)));
  __shared__ half_t Bs[2][64*128] __attribute__((aligned(16)));
  half_t* As = (half_t*)AsCs;
  float*  Cs = (float*)AsCs;
  const int tid  = threadIdx.x;
  const int i    = blockIdx.x;
  const int n0   = blockIdx.y * 8;
  const int w    = tid >> 6;
  const int lane = tid & 63;
  const int srow = tid >> 4;
  const int sc8  = tid & 15;

  for (int rep = 0; rep < reps; ++rep) {
    __syncthreads();   // rep>0: prior Cs consumers done before As overwrite

    // stage A = x[:, i, :]
    #pragma unroll
    for (int k = 0; k < 4; ++k) {
      int row  = srow + 16*k;
      const float* gp = x + ((size_t)row*II + i)*DD + sc8*8;
      float4 f0 = *(const float4*)(gp);
      float4 f1 = *(const float4*)(gp + 4);
      half8 v;
      v[0]=(half_t)f0.x; v[1]=(half_t)f0.y; v[2]=(half_t)f0.z; v[3]=(half_t)f0.w;
      v[4]=(half_t)f1.x; v[5]=(half_t)f1.y; v[6]=(half_t)f1.z; v[7]=(half_t)f1.w;
      int off = (row*256 + sc8*16) ^ ((row & 7) << 4);
      *(half8*)((char*)As + off) = v;
    }
    __syncthreads();

    // hoist A-fragments (j-invariant)
    half8 av[4];
    {
      int ra = w*16 + (lane & 15);
      #pragma unroll
      for (int kk = 0; kk < 4; ++kk) {
        int aoff = (ra*256 + kk*64 + ((lane >> 4) << 4)) ^ ((ra & 7) << 4);
        av[kk] = *(half8*)((char*)As + aoff);
      }
    }

    // prologue: stage B(j=0) into Bs[0]
    {
      const float* wbase = W + (((size_t)n0*II + i)*OO)*DD;
      #pragma unroll
      for (int k = 0; k < 4; ++k) {
        int row = srow + 16*k;
        const float* gp = wbase + row*DD + sc8*8;
        float4 f0 = *(const float4*)(gp);
        float4 f1 = *(const float4*)(gp + 4);
        half8 v;
        v[0]=(half_t)f0.x; v[1]=(half_t)f0.y; v[2]=(half_t)f0.z; v[3]=(half_t)f0.w;
        v[4]=(half_t)f1.x; v[5]=(half_t)f1.y; v[6]=(half_t)f1.z; v[7]=(half_t)f1.w;
        int off = (row*256 + sc8*16) ^ ((row & 7) << 4);
        *(half8*)((char*)Bs[0] + off) = v;
      }
    }
    __syncthreads();

    int cur = 0;
    for (int j = 0; j < 8; ++j) {
      const int n = n0 + j;

      float4 pf[8];
      if (j < 7) {
        const float* wnext = W + (((size_t)(n+1)*II + i)*OO)*DD;
        #pragma unroll
        for (int k = 0; k < 4; ++k) {
          const float* gp = wnext + (srow + 16*k)*DD + sc8*8;
          pf[2*k]   = *(const float4*)(gp);
          pf[2*k+1] = *(const float4*)(gp + 4);
        }
      }

      f32x4 acc[4];
      #pragma unroll
      for (int ot = 0; ot < 4; ++ot) acc[ot] = {0.f, 0.f, 0.f, 0.f};
      #pragma unroll
      for (int kk = 0; kk < 4; ++kk) {
        #pragma unroll
        for (int ot = 0; ot < 4; ++ot) {
          int rb   = ot*16 + (lane & 15);
          int boff = (rb*256 + kk*64 + ((lane >> 4) << 4)) ^ ((rb & 7) << 4);
          half8 bv = *(half8*)((char*)Bs[cur] + boff);
          acc[ot] = __builtin_amdgcn_mfma_f32_16x16x32_f16(av[kk], bv, acc[ot], 0, 0, 0);
        }
      }

      #pragma unroll
      for (int ot = 0; ot < 4; ++ot)
        #pragma unroll
        for (int r = 0; r < 4; ++r) {
          int row = w*16 + ((lane >> 4) << 2) + r;
          int col = ot*16 + (lane & 15);
          Cs[row*64 + col] = acc[ot][r];
        }
      __syncthreads();

      #pragma unroll
      for (int k = 0; k < 2; ++k) {
        int flat = tid + 256*k;
        int row  = flat >> 3;
        int c8   = flat & 7;
        const float* sp = Cs + row*64 + c8*8;
        half8 v;
        #pragma unroll
        for (int e = 0; e < 8; ++e) v[e] = (half_t)sp[e];
        *(half8*)(u + (((size_t)row*NN + n)*II + i)*OO + c8*8) = v;
      }

      if (j < 7) {
        #pragma unroll
        for (int k = 0; k < 4; ++k) {
          int row = srow + 16*k;
          float4 f0 = pf[2*k], f1 = pf[2*k+1];
          half8 v;
          v[0]=(half_t)f0.x; v[1]=(half_t)f0.y; v[2]=(half_t)f0.z; v[3]=(half_t)f0.w;
          v[4]=(half_t)f1.x; v[5]=(half_t)f1.y; v[6]=(half_t)f1.z; v[7]=(half_t)f1.w;
          int off = (row*256 + sc8*16) ^ ((row & 7) << 4);
          *(half8*)((char*)Bs[cur^1] + off) = v;
        }
      }
      __syncthreads();
      cur ^= 1;
    }
  }
}

// ---------------------------------------------------------------------------
// K2: out0[b,n,o] = (1/32) * sum_i u[b,n,i,o]   (reps-wrapped)
// ---------------------------------------------------------------------------
__global__ __launch_bounds__(256) void k_round0(
    const half_t* __restrict__ u, float* __restrict__ out0, int reps)
{
  __shared__ float sPart[32*65];
  const int tid = threadIdx.x;
  const int bn  = blockIdx.x;
  const int ip  = tid >> 3;
  const int o8  = tid & 7;
  const half_t* base = u + (size_t)bn * (II*OO);

  for (int rep = 0; rep < reps; ++rep) {
    float a[8];
    #pragma unroll
    for (int e = 0; e < 8; ++e) a[e] = 0.f;
    for (int i = ip; i < II; i += 32) {
      float t[8];
      load8u(base + (size_t)i*OO + o8*8, t);
      #pragma unroll
      for (int e = 0; e < 8; ++e) a[e] += t[e];
    }
    #pragma unroll
    for (int e = 0; e < 8; ++e) sPart[ip*65 + o8*8 + e] = a[e];
    for (int step = 16; step >= 1; step >>= 1) {
      __syncthreads();
      if (ip < step) {
        #pragma unroll
        for (int e = 0; e < 8; ++e)
          sPart[ip*65 + o8*8 + e] += sPart[(ip+step)*65 + o8*8 + e];
      }
    }
    __syncthreads();
    if (tid < 64) out0[(size_t)bn*OO + tid] = sPart[tid] * (1.f/32.f);
    __syncthreads();   // rep boundary: final reads done before next writes
  }
}

// ---------------------------------------------------------------------------
// K3: register-fused routing round (round-10 body, validated), reps-wrapped.
// ---------------------------------------------------------------------------
__global__ __launch_bounds__(256, 4) void k_round_reg(
    const half_t* __restrict__ u, const float* __restrict__ out_prev,
    float* __restrict__ part, int reps)
{
  __shared__ float sOut[NN*OO];
  __shared__ float sP[NN][8][9];
  __shared__ float sLog[8][NN+1];
  __shared__ float sC[8][NN+1];
  const int tid = threadIdx.x;
  const int ic  = blockIdx.x;
  const int b   = blockIdx.y;
  const int n   = tid >> 3;
  const int q   = tid & 7;

  for (int rep = 0; rep < reps; ++rep) {
    __syncthreads();   // rep>0: prior sC/sP readers done
    for (int k = 0; k < 8; ++k) {
      int flat = tid + 256*k;
      sOut[flat] = out_prev[(size_t)b*NN*OO + flat];
    }
    float a8[8];
    #pragma unroll
    for (int e = 0; e < 8; ++e) a8[e] = 0.f;
    __syncthreads();

    const half_t* ubase = u + ((size_t)b*NN + n)*II*OO;
    for (int s = 0; s < 4; ++s) {
      const int i0 = ic*32 + s*8;
      float r[8][8];
      #pragma unroll
      for (int ii = 0; ii < 8; ++ii) {
        load8u(ubase + (size_t)(i0+ii)*OO + q*8, r[ii]);
        float acc = 0.f;
        #pragma unroll
        for (int e = 0; e < 8; ++e) acc += r[ii][e] * sOut[n*OO + q*8 + e];
        sP[n][ii][q] = acc;
      }
      __syncthreads();
      {
        float sum = 0.f;
        #pragma unroll
        for (int q2 = 0; q2 < 8; ++q2) sum += sP[n][q][q2];
        sLog[q][n] = sum;
      }
      __syncthreads();
      {
        float m = -1e30f;
        #pragma unroll
        for (int n2 = 0; n2 < NN; ++n2) m = fmaxf(m, sLog[q][n2]);
        float ss = 0.f;
        #pragma unroll
        for (int n2 = 0; n2 < NN; ++n2) ss += __expf(sLog[q][n2] - m);
        sC[q][n] = __expf(sLog[q][n] - m) / ss;
      }
      __syncthreads();
      #pragma unroll
      for (int ii = 0; ii < 8; ++ii) {
        float cv = sC[ii][n];
        #pragma unroll
        for (int e = 0; e < 8; ++e) a8[e] += cv * r[ii][e];
      }
    }
    float* dst = part + (((size_t)ic*BB + b)*NN + n)*OO + q*8;
    #pragma unroll
    for (int e = 0; e < 8; ++e) dst[e] = a8[e];
  }
}

// ---------------------------------------------------------------------------
// K3b: out_next[j] = sum_{k<16} part[k][j], fixed order.
// ---------------------------------------------------------------------------
__global__ __launch_bounds__(256) void k_reduce_part(
    const float* __restrict__ part, float* __restrict__ out_next)
{
  const int j = blockIdx.x*256 + threadIdx.x;
  const size_t O = (size_t)BB*NN*OO;
  float s = 0.f;
  #pragma unroll
  for (int k = 0; k < 16; ++k) s += part[(size_t)k*O + j];
  out_next[j] = s;
}

// ---------------------------------------------------------------------------
// K4: fused final reduce + lengths
// ---------------------------------------------------------------------------
__global__ __launch_bounds__(64) void k_reduce_len(
    const float* __restrict__ part, float* __restrict__ dout)
{
  const int bn = blockIdx.x;
  const int o  = threadIdx.x;
  const size_t O = (size_t)BB*NN*OO;
  float s = 0.f;
  #pragma unroll
  for (int k = 0; k < 16; ++k) s += part[(size_t)k*O + (size_t)bn*OO + o];
  float sq = s * s;
  #pragma unroll
  for (int d = 32; d >= 1; d >>= 1) sq += __shfl_xor(sq, d, 64);
  if (o == 0) dout[bn] = sqrtf(sq);
}

extern "C" void kernel_launch(void* const* d_in, const int* in_sizes, int n_in,
                              void* d_out, int out_size, void* d_ws, size_t ws_size,
                              hipStream_t stream)
{
  const float* x = (const float*)d_in[0];
  const float* W = (const float*)d_in[1];
  float* dout = (float*)d_out;

  const size_t U = (size_t)BB*NN*II*OO;
  const size_t O = (size_t)BB*NN*OO;

  half_t* u    = (half_t*)d_ws;
  float* out0  = (float*)((char*)d_ws + U*2);
  float* out1  = out0 + O;
  float* part1 = out1 + O;                 // 16*O
  float* part2 = part1 + 16*O;             // 16*O

  k_compute_u  <<<dim3(II, 4),  dim3(256), 0, stream>>>(x, W, u, REPS_K1);
  k_round0     <<<dim3(BB*NN),  dim3(256), 0, stream>>>(u, out0, REPS_R0);
  k_round_reg  <<<dim3(16, BB), dim3(256), 0, stream>>>(u, out0, part1, REPS_RR);
  k_reduce_part<<<dim3(512),    dim3(256), 0, stream>>>(part1, out1);
  k_round_reg  <<<dim3(16, BB), dim3(256), 0, stream>>>(u, out1, part2, REPS_RR);
  k_reduce_len <<<dim3(BB*NN),  dim3(64),  0, stream>>>(part2, dout);
}

// Round 12
// 397.443 us; speedup vs baseline: 4.6036x; 4.6036x over previous
//
#include <hip/hip_runtime.h>

typedef _Float16 half_t;
typedef __attribute__((ext_vector_type(8))) _Float16 half8;
typedef __attribute__((ext_vector_type(4))) float f32x4;

#define BB 64
#define II 512
#define DD 128
#define NN 32
#define OO 64

// load 8 contiguous u-elements (fp16) as fp32
__device__ inline void load8u(const half_t* p, float* a) {
  half8 v = *(const half8*)p;
  #pragma unroll
  for (int e = 0; e < 8; ++e) a[e] = (float)v[e];
}

// ---------------------------------------------------------------------------
// K1: u[b,n,i,o] = sum_d x[b,i,d] * W[n,i,o,d] via fp16 MFMA (round-10 body,
// validated; ~120us, within ~15% of its 104us traffic floor per r11 diag).
// ---------------------------------------------------------------------------
__global__ __launch_bounds__(256) void k_compute_u(
    const float* __restrict__ x, const float* __restrict__ W,
    half_t* __restrict__ u)
{
  __shared__ unsigned char AsCs[16384] __attribute__((aligned(16)));
  __shared__ half_t Bs[2][64*128] __attribute__((aligned(16)));
  half_t* As = (half_t*)AsCs;
  float*  Cs = (float*)AsCs;
  const int tid  = threadIdx.x;
  const int i    = blockIdx.x;
  const int n0   = blockIdx.y * 8;
  const int w    = tid >> 6;
  const int lane = tid & 63;
  const int srow = tid >> 4;
  const int sc8  = tid & 15;

  // stage A = x[:, i, :]
  #pragma unroll
  for (int k = 0; k < 4; ++k) {
    int row  = srow + 16*k;
    const float* gp = x + ((size_t)row*II + i)*DD + sc8*8;
    float4 f0 = *(const float4*)(gp);
    float4 f1 = *(const float4*)(gp + 4);
    half8 v;
    v[0]=(half_t)f0.x; v[1]=(half_t)f0.y; v[2]=(half_t)f0.z; v[3]=(half_t)f0.w;
    v[4]=(half_t)f1.x; v[5]=(half_t)f1.y; v[6]=(half_t)f1.z; v[7]=(half_t)f1.w;
    int off = (row*256 + sc8*16) ^ ((row & 7) << 4);
    *(half8*)((char*)As + off) = v;
  }
  __syncthreads();

  // hoist A-fragments (j-invariant)
  half8 av[4];
  {
    int ra = w*16 + (lane & 15);
    #pragma unroll
    for (int kk = 0; kk < 4; ++kk) {
      int aoff = (ra*256 + kk*64 + ((lane >> 4) << 4)) ^ ((ra & 7) << 4);
      av[kk] = *(half8*)((char*)As + aoff);
    }
  }

  // prologue: stage B(j=0) into Bs[0]
  {
    const float* wbase = W + (((size_t)n0*II + i)*OO)*DD;
    #pragma unroll
    for (int k = 0; k < 4; ++k) {
      int row = srow + 16*k;
      const float* gp = wbase + row*DD + sc8*8;
      float4 f0 = *(const float4*)(gp);
      float4 f1 = *(const float4*)(gp + 4);
      half8 v;
      v[0]=(half_t)f0.x; v[1]=(half_t)f0.y; v[2]=(half_t)f0.z; v[3]=(half_t)f0.w;
      v[4]=(half_t)f1.x; v[5]=(half_t)f1.y; v[6]=(half_t)f1.z; v[7]=(half_t)f1.w;
      int off = (row*256 + sc8*16) ^ ((row & 7) << 4);
      *(half8*)((char*)Bs[0] + off) = v;
    }
  }
  __syncthreads();

  int cur = 0;
  for (int j = 0; j < 8; ++j) {
    const int n = n0 + j;

    float4 pf[8];
    if (j < 7) {
      const float* wnext = W + (((size_t)(n+1)*II + i)*OO)*DD;
      #pragma unroll
      for (int k = 0; k < 4; ++k) {
        const float* gp = wnext + (srow + 16*k)*DD + sc8*8;
        pf[2*k]   = *(const float4*)(gp);
        pf[2*k+1] = *(const float4*)(gp + 4);
      }
    }

    f32x4 acc[4];
    #pragma unroll
    for (int ot = 0; ot < 4; ++ot) acc[ot] = {0.f, 0.f, 0.f, 0.f};
    #pragma unroll
    for (int kk = 0; kk < 4; ++kk) {
      #pragma unroll
      for (int ot = 0; ot < 4; ++ot) {
        int rb   = ot*16 + (lane & 15);
        int boff = (rb*256 + kk*64 + ((lane >> 4) << 4)) ^ ((rb & 7) << 4);
        half8 bv = *(half8*)((char*)Bs[cur] + boff);
        acc[ot] = __builtin_amdgcn_mfma_f32_16x16x32_f16(av[kk], bv, acc[ot], 0, 0, 0);
      }
    }

    // D lane map: col = lane&15, row = (lane>>4)*4 + r  (m89-verified)
    #pragma unroll
    for (int ot = 0; ot < 4; ++ot)
      #pragma unroll
      for (int r = 0; r < 4; ++r) {
        int row = w*16 + ((lane >> 4) << 2) + r;
        int col = ot*16 + (lane & 15);
        Cs[row*64 + col] = acc[ot][r];
      }
    __syncthreads();

    #pragma unroll
    for (int k = 0; k < 2; ++k) {
      int flat = tid + 256*k;
      int row  = flat >> 3;
      int c8   = flat & 7;
      const float* sp = Cs + row*64 + c8*8;
      half8 v;
      #pragma unroll
      for (int e = 0; e < 8; ++e) v[e] = (half_t)sp[e];
      *(half8*)(u + (((size_t)row*NN + n)*II + i)*OO + c8*8) = v;
    }

    if (j < 7) {
      #pragma unroll
      for (int k = 0; k < 4; ++k) {
        int row = srow + 16*k;
        float4 f0 = pf[2*k], f1 = pf[2*k+1];
        half8 v;
        v[0]=(half_t)f0.x; v[1]=(half_t)f0.y; v[2]=(half_t)f0.z; v[3]=(half_t)f0.w;
        v[4]=(half_t)f1.x; v[5]=(half_t)f1.y; v[6]=(half_t)f1.z; v[7]=(half_t)f1.w;
        int off = (row*256 + sc8*16) ^ ((row & 7) << 4);
        *(half8*)((char*)Bs[cur^1] + off) = v;
      }
    }
    __syncthreads();
    cur ^= 1;
  }
}

// ---------------------------------------------------------------------------
// K2: out0[b,n,o] = (1/32) * sum_i u[b,n,i,o]   (validated rounds 3-11)
// ---------------------------------------------------------------------------
__global__ __launch_bounds__(256) void k_round0(
    const half_t* __restrict__ u, float* __restrict__ out0)
{
  __shared__ float sPart[32*65];
  const int tid = threadIdx.x;
  const int bn  = blockIdx.x;
  const int ip  = tid >> 3;
  const int o8  = tid & 7;
  const half_t* base = u + (size_t)bn * (II*OO);
  float a[8];
  #pragma unroll
  for (int e = 0; e < 8; ++e) a[e] = 0.f;
  for (int i = ip; i < II; i += 32) {
    float t[8];
    load8u(base + (size_t)i*OO + o8*8, t);
    #pragma unroll
    for (int e = 0; e < 8; ++e) a[e] += t[e];
  }
  #pragma unroll
  for (int e = 0; e < 8; ++e) sPart[ip*65 + o8*8 + e] = a[e];
  for (int step = 16; step >= 1; step >>= 1) {
    __syncthreads();
    if (ip < step) {
      #pragma unroll
      for (int e = 0; e < 8; ++e)
        sPart[ip*65 + o8*8 + e] += sPart[(ip+step)*65 + o8*8 + e];
    }
  }
  __syncthreads();
  if (tid < 64) out0[(size_t)bn*OO + tid] = sPart[tid] * (1.f/32.f);
}

// ---------------------------------------------------------------------------
// K3: register-fused routing round. r11-diag-driven rework:
//  - out_prev slice hoisted to fp32 REGISTERS (kills sOut LDS + its 8-way
//    bank conflict, the 10.2M conflict cycles seen in r11)
//  - u-tile kept in fp16 registers (half8 r16[8] = 32 VGPR) so live state
//    fits 64 VGPR -> __launch_bounds__(256,8), 8 blocks/CU
//  - 16 i per block, grid (32, B) = 2048 blocks -> 8/CU for latency hiding
// Deterministic: plain stores, fixed-order sums, redundant softmax.
// ---------------------------------------------------------------------------
__global__ __launch_bounds__(256, 8) void k_round_reg(
    const half_t* __restrict__ u, const float* __restrict__ out_prev,
    float* __restrict__ part)
{
  __shared__ float sP[NN][8][9];       // 9216 B, 2-way max (free)
  __shared__ float sLog[8][NN+1];
  __shared__ float sC[8][NN+1];
  const int tid = threadIdx.x;
  const int ic  = blockIdx.x;          // 0..31
  const int b   = blockIdx.y;
  const int n   = tid >> 3;
  const int q   = tid & 7;

  // out_prev[b, n, q*8..q*8+7] -> registers (the only slice this thread uses)
  float so[8];
  {
    const float* op = out_prev + (size_t)b*NN*OO + n*OO + q*8;
    f32x4 v0 = *(const f32x4*)op;
    f32x4 v1 = *(const f32x4*)(op + 4);
    so[0]=v0[0]; so[1]=v0[1]; so[2]=v0[2]; so[3]=v0[3];
    so[4]=v1[0]; so[5]=v1[1]; so[6]=v1[2]; so[7]=v1[3];
  }
  float a8[8];
  #pragma unroll
  for (int e = 0; e < 8; ++e) a8[e] = 0.f;

  const half_t* ubase = u + ((size_t)b*NN + n)*II*OO;
  for (int s = 0; s < 2; ++s) {
    const int i0 = ic*16 + s*8;
    half8 r16[8];
    // phase 1: load 8 i-rows (fp16 regs) + partial logit dots (fp32 acc)
    #pragma unroll
    for (int ii = 0; ii < 8; ++ii) {
      r16[ii] = *(const half8*)(ubase + (size_t)(i0+ii)*OO + q*8);
      float acc = 0.f;
      #pragma unroll
      for (int e = 0; e < 8; ++e) acc += (float)r16[ii][e] * so[e];
      sP[n][ii][q] = acc;
    }
    __syncthreads();
    // logits: thread (n,q) reduces ii = q over the 8 o-chunks
    {
      float sum = 0.f;
      #pragma unroll
      for (int q2 = 0; q2 < 8; ++q2) sum += sP[n][q][q2];
      sLog[q][n] = sum;
    }
    __syncthreads();
    // softmax over n for ii = q (redundant, fixed order -> deterministic)
    {
      float m = -1e30f;
      #pragma unroll
      for (int n2 = 0; n2 < NN; ++n2) m = fmaxf(m, sLog[q][n2]);
      float ss = 0.f;
      #pragma unroll
      for (int n2 = 0; n2 < NN; ++n2) ss += __expf(sLog[q][n2] - m);
      sC[q][n] = __expf(sLog[q][n] - m) / ss;
    }
    __syncthreads();
    // phase 2: from the fp16 register tile, fp32 accumulate
    #pragma unroll
    for (int ii = 0; ii < 8; ++ii) {
      float cv = sC[ii][n];
      #pragma unroll
      for (int e = 0; e < 8; ++e) a8[e] += cv * (float)r16[ii][e];
    }
    // no trailing barrier: next sP writes are disjoint from sC; the next
    // sC write is 2 barriers downstream of every thread's phase-2 reads.
  }
  float* dst = part + (((size_t)ic*BB + b)*NN + n)*OO + q*8;
  #pragma unroll
  for (int e = 0; e < 8; ++e) dst[e] = a8[e];
}

// ---------------------------------------------------------------------------
// K3b: out_next[j] = sum_{k<32} part[k][j], fixed order.
// ---------------------------------------------------------------------------
__global__ __launch_bounds__(256) void k_reduce_part(
    const float* __restrict__ part, float* __restrict__ out_next)
{
  const int j = blockIdx.x*256 + threadIdx.x;   // grid = 512
  const size_t O = (size_t)BB*NN*OO;
  float s = 0.f;
  #pragma unroll
  for (int k = 0; k < 32; ++k) s += part[(size_t)k*O + j];
  out_next[j] = s;
}

// ---------------------------------------------------------------------------
// K4: fused final reduce + lengths
// ---------------------------------------------------------------------------
__global__ __launch_bounds__(64) void k_reduce_len(
    const float* __restrict__ part, float* __restrict__ dout)
{
  const int bn = blockIdx.x;
  const int o  = threadIdx.x;
  const size_t O = (size_t)BB*NN*OO;
  float s = 0.f;
  #pragma unroll
  for (int k = 0; k < 32; ++k) s += part[(size_t)k*O + (size_t)bn*OO + o];
  float sq = s * s;
  #pragma unroll
  for (int d = 32; d >= 1; d >>= 1) sq += __shfl_xor(sq, d, 64);
  if (o == 0) dout[bn] = sqrtf(sq);
}

extern "C" void kernel_launch(void* const* d_in, const int* in_sizes, int n_in,
                              void* d_out, int out_size, void* d_ws, size_t ws_size,
                              hipStream_t stream)
{
  const float* x = (const float*)d_in[0];
  const float* W = (const float*)d_in[1];
  float* dout = (float*)d_out;

  const size_t U = (size_t)BB*NN*II*OO;
  const size_t O = (size_t)BB*NN*OO;

  half_t* u   = (half_t*)d_ws;                      // 128 MiB fp16
  float* out0 = (float*)((char*)d_ws + U*2);
  float* out1 = out0 + O;
  float* part = out1 + O;                           // 32*O floats = 16 MiB

  k_compute_u  <<<dim3(II, 4),  dim3(256), 0, stream>>>(x, W, u);
  k_round0     <<<dim3(BB*NN),  dim3(256), 0, stream>>>(u, out0);
  k_round_reg  <<<dim3(32, BB), dim3(256), 0, stream>>>(u, out0, part);
  k_reduce_part<<<dim3(512),    dim3(256), 0, stream>>>(part, out1);
  k_round_reg  <<<dim3(32, BB), dim3(256), 0, stream>>>(u, out1, part);
  k_reduce_len <<<dim3(BB*NN),  dim3(64),  0, stream>>>(part, dout);
}

// Round 13
// 214.304 us; speedup vs baseline: 8.5378x; 1.8546x over previous
//
#include <hip/hip_runtime.h>

typedef _Float16 half_t;
typedef __attribute__((ext_vector_type(8))) _Float16 half8;
typedef __attribute__((ext_vector_type(4))) float f32x4;

#define BB 64
#define II 512
#define DD 128
#define NN 32
#define OO 64

// load 8 contiguous u-elements (fp16) as fp32
__device__ inline void load8u(const half_t* p, float* a) {
  half8 v = *(const half8*)p;
  #pragma unroll
  for (int e = 0; e < 8; ++e) a[e] = (float)v[e];
}

// ---------------------------------------------------------------------------
// K1: u[b,n,i,o] = sum_d x[b,i,d] * W[n,i,o,d] via fp16 MFMA (round-10 body,
// validated; ~120us, within ~15% of its 104us traffic floor per r11 diag).
// ---------------------------------------------------------------------------
__global__ __launch_bounds__(256) void k_compute_u(
    const float* __restrict__ x, const float* __restrict__ W,
    half_t* __restrict__ u)
{
  __shared__ unsigned char AsCs[16384] __attribute__((aligned(16)));
  __shared__ half_t Bs[2][64*128] __attribute__((aligned(16)));
  half_t* As = (half_t*)AsCs;
  float*  Cs = (float*)AsCs;
  const int tid  = threadIdx.x;
  const int i    = blockIdx.x;
  const int n0   = blockIdx.y * 8;
  const int w    = tid >> 6;
  const int lane = tid & 63;
  const int srow = tid >> 4;
  const int sc8  = tid & 15;

  // stage A = x[:, i, :]
  #pragma unroll
  for (int k = 0; k < 4; ++k) {
    int row  = srow + 16*k;
    const float* gp = x + ((size_t)row*II + i)*DD + sc8*8;
    float4 f0 = *(const float4*)(gp);
    float4 f1 = *(const float4*)(gp + 4);
    half8 v;
    v[0]=(half_t)f0.x; v[1]=(half_t)f0.y; v[2]=(half_t)f0.z; v[3]=(half_t)f0.w;
    v[4]=(half_t)f1.x; v[5]=(half_t)f1.y; v[6]=(half_t)f1.z; v[7]=(half_t)f1.w;
    int off = (row*256 + sc8*16) ^ ((row & 7) << 4);
    *(half8*)((char*)As + off) = v;
  }
  __syncthreads();

  // hoist A-fragments (j-invariant)
  half8 av[4];
  {
    int ra = w*16 + (lane & 15);
    #pragma unroll
    for (int kk = 0; kk < 4; ++kk) {
      int aoff = (ra*256 + kk*64 + ((lane >> 4) << 4)) ^ ((ra & 7) << 4);
      av[kk] = *(half8*)((char*)As + aoff);
    }
  }

  // prologue: stage B(j=0) into Bs[0]
  {
    const float* wbase = W + (((size_t)n0*II + i)*OO)*DD;
    #pragma unroll
    for (int k = 0; k < 4; ++k) {
      int row = srow + 16*k;
      const float* gp = wbase + row*DD + sc8*8;
      float4 f0 = *(const float4*)(gp);
      float4 f1 = *(const float4*)(gp + 4);
      half8 v;
      v[0]=(half_t)f0.x; v[1]=(half_t)f0.y; v[2]=(half_t)f0.z; v[3]=(half_t)f0.w;
      v[4]=(half_t)f1.x; v[5]=(half_t)f1.y; v[6]=(half_t)f1.z; v[7]=(half_t)f1.w;
      int off = (row*256 + sc8*16) ^ ((row & 7) << 4);
      *(half8*)((char*)Bs[0] + off) = v;
    }
  }
  __syncthreads();

  int cur = 0;
  for (int j = 0; j < 8; ++j) {
    const int n = n0 + j;

    float4 pf[8];
    if (j < 7) {
      const float* wnext = W + (((size_t)(n+1)*II + i)*OO)*DD;
      #pragma unroll
      for (int k = 0; k < 4; ++k) {
        const float* gp = wnext + (srow + 16*k)*DD + sc8*8;
        pf[2*k]   = *(const float4*)(gp);
        pf[2*k+1] = *(const float4*)(gp + 4);
      }
    }

    f32x4 acc[4];
    #pragma unroll
    for (int ot = 0; ot < 4; ++ot) acc[ot] = {0.f, 0.f, 0.f, 0.f};
    #pragma unroll
    for (int kk = 0; kk < 4; ++kk) {
      #pragma unroll
      for (int ot = 0; ot < 4; ++ot) {
        int rb   = ot*16 + (lane & 15);
        int boff = (rb*256 + kk*64 + ((lane >> 4) << 4)) ^ ((rb & 7) << 4);
        half8 bv = *(half8*)((char*)Bs[cur] + boff);
        acc[ot] = __builtin_amdgcn_mfma_f32_16x16x32_f16(av[kk], bv, acc[ot], 0, 0, 0);
      }
    }

    // D lane map: col = lane&15, row = (lane>>4)*4 + r  (m89-verified)
    #pragma unroll
    for (int ot = 0; ot < 4; ++ot)
      #pragma unroll
      for (int r = 0; r < 4; ++r) {
        int row = w*16 + ((lane >> 4) << 2) + r;
        int col = ot*16 + (lane & 15);
        Cs[row*64 + col] = acc[ot][r];
      }
    __syncthreads();

    #pragma unroll
    for (int k = 0; k < 2; ++k) {
      int flat = tid + 256*k;
      int row  = flat >> 3;
      int c8   = flat & 7;
      const float* sp = Cs + row*64 + c8*8;
      half8 v;
      #pragma unroll
      for (int e = 0; e < 8; ++e) v[e] = (half_t)sp[e];
      *(half8*)(u + (((size_t)row*NN + n)*II + i)*OO + c8*8) = v;
    }

    if (j < 7) {
      #pragma unroll
      for (int k = 0; k < 4; ++k) {
        int row = srow + 16*k;
        float4 f0 = pf[2*k], f1 = pf[2*k+1];
        half8 v;
        v[0]=(half_t)f0.x; v[1]=(half_t)f0.y; v[2]=(half_t)f0.z; v[3]=(half_t)f0.w;
        v[4]=(half_t)f1.x; v[5]=(half_t)f1.y; v[6]=(half_t)f1.z; v[7]=(half_t)f1.w;
        int off = (row*256 + sc8*16) ^ ((row & 7) << 4);
        *(half8*)((char*)Bs[cur^1] + off) = v;
      }
    }
    __syncthreads();
    cur ^= 1;
  }
}

// ---------------------------------------------------------------------------
// K2: out0[b,n,o] = (1/32) * sum_i u[b,n,i,o]   (validated rounds 3-12)
// ---------------------------------------------------------------------------
__global__ __launch_bounds__(256) void k_round0(
    const half_t* __restrict__ u, float* __restrict__ out0)
{
  __shared__ float sPart[32*65];
  const int tid = threadIdx.x;
  const int bn  = blockIdx.x;
  const int ip  = tid >> 3;
  const int o8  = tid & 7;
  const half_t* base = u + (size_t)bn * (II*OO);
  float a[8];
  #pragma unroll
  for (int e = 0; e < 8; ++e) a[e] = 0.f;
  for (int i = ip; i < II; i += 32) {
    float t[8];
    load8u(base + (size_t)i*OO + o8*8, t);
    #pragma unroll
    for (int e = 0; e < 8; ++e) a[e] += t[e];
  }
  #pragma unroll
  for (int e = 0; e < 8; ++e) sPart[ip*65 + o8*8 + e] = a[e];
  for (int step = 16; step >= 1; step >>= 1) {
    __syncthreads();
    if (ip < step) {
      #pragma unroll
      for (int e = 0; e < 8; ++e)
        sPart[ip*65 + o8*8 + e] += sPart[(ip+step)*65 + o8*8 + e];
    }
  }
  __syncthreads();
  if (tid < 64) out0[(size_t)bn*OO + tid] = sPart[tid] * (1.f/32.f);
}

// ---------------------------------------------------------------------------
// K3: register-fused routing round. Round-10 geometry (16 chunks, 32 i/block,
// 4 sub-rounds, launch_bounds(256,4) = 128 VGPR cap -> NO spill), with the
// two r11-diag fixes that fit that budget:
//  - out_prev slice in fp32 registers (kills the 10.2M-cycle sOut bank
//    conflict; removes one barrier)
//  - u-tile in fp16 registers (32 VGPR vs 64) so phase 2 truly runs from regs
// r12's (256,8) 64-VGPR spill regression reverted.
// ---------------------------------------------------------------------------
__global__ __launch_bounds__(256, 4) void k_round_reg(
    const half_t* __restrict__ u, const float* __restrict__ out_prev,
    float* __restrict__ part)
{
  __shared__ float sP[NN][8][9];       // 9216 B; worst aliasing 2-way (free)
  __shared__ float sLog[8][NN+1];
  __shared__ float sC[8][NN+1];
  const int tid = threadIdx.x;
  const int ic  = blockIdx.x;          // 0..15
  const int b   = blockIdx.y;
  const int n   = tid >> 3;
  const int q   = tid & 7;

  // out_prev[b, n, q*8..q*8+7] -> registers (the only slice this thread uses)
  float so[8];
  {
    const float* op = out_prev + (size_t)b*NN*OO + n*OO + q*8;
    f32x4 v0 = *(const f32x4*)op;
    f32x4 v1 = *(const f32x4*)(op + 4);
    so[0]=v0[0]; so[1]=v0[1]; so[2]=v0[2]; so[3]=v0[3];
    so[4]=v1[0]; so[5]=v1[1]; so[6]=v1[2]; so[7]=v1[3];
  }
  float a8[8];
  #pragma unroll
  for (int e = 0; e < 8; ++e) a8[e] = 0.f;

  const half_t* ubase = u + ((size_t)b*NN + n)*II*OO;
  for (int s = 0; s < 4; ++s) {
    const int i0 = ic*32 + s*8;
    half8 r16[8];
    // phase 1: load 8 i-rows (fp16 regs) + partial logit dots (fp32)
    #pragma unroll
    for (int ii = 0; ii < 8; ++ii) {
      r16[ii] = *(const half8*)(ubase + (size_t)(i0+ii)*OO + q*8);
      float acc = 0.f;
      #pragma unroll
      for (int e = 0; e < 8; ++e) acc += (float)r16[ii][e] * so[e];
      sP[n][ii][q] = acc;
    }
    __syncthreads();
    // logits: thread (n,q) reduces ii = q over the 8 o-chunks
    {
      float sum = 0.f;
      #pragma unroll
      for (int q2 = 0; q2 < 8; ++q2) sum += sP[n][q][q2];
      sLog[q][n] = sum;
    }
    __syncthreads();
    // softmax over n for ii = q (redundant, fixed order -> deterministic)
    {
      float m = -1e30f;
      #pragma unroll
      for (int n2 = 0; n2 < NN; ++n2) m = fmaxf(m, sLog[q][n2]);
      float ss = 0.f;
      #pragma unroll
      for (int n2 = 0; n2 < NN; ++n2) ss += __expf(sLog[q][n2] - m);
      sC[q][n] = __expf(sLog[q][n] - m) / ss;
    }
    __syncthreads();
    // phase 2: from the fp16 register tile, fp32 accumulate
    #pragma unroll
    for (int ii = 0; ii < 8; ++ii) {
      float cv = sC[ii][n];
      #pragma unroll
      for (int e = 0; e < 8; ++e) a8[e] += cv * (float)r16[ii][e];
    }
    // next sP write is 1 barrier downstream of sC reads via the post-phase1
    // barrier of iteration s+1; sC itself is rewritten 2 barriers later.
    // (structure identical to r12, which validated at absmax 2.0)
  }
  float* dst = part + (((size_t)ic*BB + b)*NN + n)*OO + q*8;
  #pragma unroll
  for (int e = 0; e < 8; ++e) dst[e] = a8[e];
}

// ---------------------------------------------------------------------------
// K3b: out_next[j] = sum_{k<16} part[k][j], fixed order.
// ---------------------------------------------------------------------------
__global__ __launch_bounds__(256) void k_reduce_part(
    const float* __restrict__ part, float* __restrict__ out_next)
{
  const int j = blockIdx.x*256 + threadIdx.x;   // grid = 512
  const size_t O = (size_t)BB*NN*OO;
  float s = 0.f;
  #pragma unroll
  for (int k = 0; k < 16; ++k) s += part[(size_t)k*O + j];
  out_next[j] = s;
}

// ---------------------------------------------------------------------------
// K4: fused final reduce + lengths
// ---------------------------------------------------------------------------
__global__ __launch_bounds__(64) void k_reduce_len(
    const float* __restrict__ part, float* __restrict__ dout)
{
  const int bn = blockIdx.x;
  const int o  = threadIdx.x;
  const size_t O = (size_t)BB*NN*OO;
  float s = 0.f;
  #pragma unroll
  for (int k = 0; k < 16; ++k) s += part[(size_t)k*O + (size_t)bn*OO + o];
  float sq = s * s;
  #pragma unroll
  for (int d = 32; d >= 1; d >>= 1) sq += __shfl_xor(sq, d, 64);
  if (o == 0) dout[bn] = sqrtf(sq);
}

extern "C" void kernel_launch(void* const* d_in, const int* in_sizes, int n_in,
                              void* d_out, int out_size, void* d_ws, size_t ws_size,
                              hipStream_t stream)
{
  const float* x = (const float*)d_in[0];
  const float* W = (const float*)d_in[1];
  float* dout = (float*)d_out;

  const size_t U = (size_t)BB*NN*II*OO;
  const size_t O = (size_t)BB*NN*OO;

  half_t* u   = (half_t*)d_ws;                      // 128 MiB fp16
  float* out0 = (float*)((char*)d_ws + U*2);
  float* out1 = out0 + O;
  float* part = out1 + O;                           // 16*O floats = 8 MiB

  k_compute_u  <<<dim3(II, 4),  dim3(256), 0, stream>>>(x, W, u);
  k_round0     <<<dim3(BB*NN),  dim3(256), 0, stream>>>(u, out0);
  k_round_reg  <<<dim3(16, BB), dim3(256), 0, stream>>>(u, out0, part);
  k_reduce_part<<<dim3(512),    dim3(256), 0, stream>>>(part, out1);
  k_round_reg  <<<dim3(16, BB), dim3(256), 0, stream>>>(u, out1, part);
  k_reduce_len <<<dim3(BB*NN),  dim3(64),  0, stream>>>(part, dout);
}